// Round 20
// baseline (131.022 us; speedup 1.0000x reference)
//
#include <hip/hip_runtime.h>
#include <hip/hip_bf16.h>
#include <stdint.h>

#define N_TOK 8192
#define DIM   512
#define HID   2048
#define OUTD  512
#define NEXP  8

typedef short  bf16x8 __attribute__((ext_vector_type(8)));
typedef float  f32x4  __attribute__((ext_vector_type(4)));
typedef unsigned short u16x8 __attribute__((ext_vector_type(8)));

// ---- workspace layout (bytes) ----
#define WS_CNT    0        // 8 ints
#define WS_LIST   4096     // 8*8192 ints
#define WS_XBF    266240   // 8192*512 bf16
#define WS_W1T    8654848  // 8*2048*512 bf16 ([e][h][d])
#define WS_W2T    25432064 // 8*512*2048 bf16 ([e][o][h])
#define WS_H      42209280 // 8192*2048 bf16

__device__ __forceinline__ unsigned short f2bf(float f) {
    uint32_t u = __builtin_bit_cast(uint32_t, f);
    u = (u + 0x7fffu + ((u >> 16) & 1u)) >> 16;   // RNE
    return (unsigned short)u;
}

// async global->LDS, 16B/lane; LDS dest = wave-uniform base + lane*16
__device__ __forceinline__ void gload16(const void* g, void* l) {
    __builtin_amdgcn_global_load_lds(
        (const __attribute__((address_space(1))) unsigned int*)g,
        (__attribute__((address_space(3))) unsigned int*)l, 16, 0, 0);
}

#define MFMA_BF16 __builtin_amdgcn_mfma_f32_16x16x32_bf16

// ======== k1: router+convert (bid 0..255) | W1 transpose (bid 256..2303) ========
__global__ __launch_bounds__(256) void k1_kernel(
    const float* __restrict__ x, const float* __restrict__ wr, const float* __restrict__ br,
    const float* __restrict__ w1,
    float* __restrict__ probs, int* __restrict__ cnt, int* __restrict__ list,
    unsigned short* __restrict__ xbf, unsigned short* __restrict__ w1t)
{
    const int bid = blockIdx.x, tid = threadIdx.x;
    if (bid < 256) {
        __shared__ int lcnt[NEXP], lbase[NEXP];
        __shared__ int am_l[32], slot_l[32];
        const int w = tid >> 6, lane = tid & 63;
        if (tid < NEXP) lcnt[tid] = 0;
        __syncthreads();
        for (int i = 0; i < 8; i++) {
            const int n = bid * 32 + w * 8 + i;
            float acc[NEXP] = {};
            #pragma unroll
            for (int db = 0; db < 8; db++) {
                const int d = db * 64 + lane;
                const float xv = x[(size_t)n * DIM + d];
                const f32x4 wv0 = *(const f32x4*)&wr[d * 8];
                const f32x4 wv1 = *(const f32x4*)&wr[d * 8 + 4];
                #pragma unroll
                for (int e = 0; e < 4; e++) { acc[e] += xv * wv0[e]; acc[4 + e] += xv * wv1[e]; }
            }
            #pragma unroll
            for (int m = 1; m < 64; m <<= 1)
                #pragma unroll
                for (int e = 0; e < NEXP; e++) acc[e] += __shfl_xor(acc[e], m, 64);
            #pragma unroll
            for (int e = 0; e < NEXP; e++) acc[e] += br[e];
            float mx = acc[0]; int am = 0;
            #pragma unroll
            for (int e = 1; e < NEXP; e++) if (acc[e] > mx) { mx = acc[e]; am = e; }
            float p[NEXP]; float s = 0.f;
            #pragma unroll
            for (int e = 0; e < NEXP; e++) { p[e] = expf(acc[e] - mx); s += p[e]; }
            const float inv = 1.f / s;
            if (lane == 0) {
                f32x4 p0, p1;
                #pragma unroll
                for (int e = 0; e < 4; e++) { p0[e] = p[e] * inv; p1[e] = p[e + 4] * inv; }
                *(f32x4*)&probs[(size_t)n * NEXP]     = p0;
                *(f32x4*)&probs[(size_t)n * NEXP + 4] = p1;
                const int slot = atomicAdd(&lcnt[am], 1);
                am_l[w * 8 + i] = am; slot_l[w * 8 + i] = slot;
            }
        }
        __syncthreads();
        if (tid < NEXP) lbase[tid] = atomicAdd(&cnt[tid], lcnt[tid]);
        __syncthreads();
        if (tid < 32) {
            const int a = am_l[tid];
            list[a * N_TOK + lbase[a] + slot_l[tid]] = bid * 32 + tid;
        }
        const int row = bid * 32 + (tid >> 3), seg = tid & 7;
        const float* src = x + (size_t)row * DIM + seg * 64;
        unsigned short* dst = xbf + (size_t)row * DIM + seg * 64;
        #pragma unroll
        for (int j = 0; j < 8; j++) {
            f32x4 a = *(const f32x4*)&src[j * 8];
            f32x4 b = *(const f32x4*)&src[j * 8 + 4];
            u16x8 o;
            #pragma unroll
            for (int q2 = 0; q2 < 4; q2++) { o[q2] = f2bf(a[q2]); o[4 + q2] = f2bf(b[q2]); }
            *(u16x8*)&dst[j * 8] = o;
        }
    } else {
        __shared__ float t[64][65];
        const int loc = bid - 256, e = loc >> 8, l2 = loc & 255;   // 8 r x 32 c
        const float* pin = w1 + (size_t)e * DIM * HID;
        unsigned short* pout = w1t + (size_t)e * DIM * HID;
        const int r0 = (l2 >> 5) * 64, c0 = (l2 & 31) * 64;
        const int r = tid >> 2, q = tid & 3;
        #pragma unroll
        for (int j = 0; j < 4; j++) {
            f32x4 v = *(const f32x4*)&pin[(size_t)(r0 + r) * HID + c0 + q * 16 + j * 4];
            #pragma unroll
            for (int i = 0; i < 4; i++) t[r][q * 16 + j * 4 + i] = v[i];
        }
        __syncthreads();
        unsigned short o[16];
        #pragma unroll
        for (int i = 0; i < 16; i++) o[i] = f2bf(t[q * 16 + i][r]);
        unsigned short* dst = &pout[(size_t)(c0 + r) * DIM + r0 + q * 16];
        *(u16x8*)dst       = *(const u16x8*)&o[0];
        *(u16x8*)(dst + 8) = *(const u16x8*)&o[8];
    }
}

// bijective per-XCD chunk swizzle
__device__ __forceinline__ int xcd_swizzle(int bid, int nwg, bool& valid) {
    const int xcd = bid & 7, cidx = bid >> 3;
    const int q = nwg >> 3, r = nwg & 7;
    const int csz = q + (xcd < r ? 1 : 0);
    valid = (cidx < csz);
    return (xcd < r ? xcd * (q + 1) : r * (q + 1) + (xcd - r) * q) + cidx;
}

// mt -> (expert, row0, base) from cnt[8]; 128-row tiles
__device__ __forceinline__ void tile_map128(const int* __restrict__ cnt, int tile,
                                            int& e, int& row0, int& bs, int& m_e, int& ntiles) {
    int c[NEXP]; ntiles = 0;
    #pragma unroll
    for (int i = 0; i < NEXP; i++) { c[i] = cnt[i]; ntiles += (c[i] + 127) >> 7; }
    int t = tile, b = 0, ei = 0;
    #pragma unroll
    for (int i = 0; i < NEXP; i++) {
        const int nt = (c[i] + 127) >> 7;
        if (t >= 0 && t < nt) { ei = i; row0 = t << 7; bs = b; m_e = c[i]; }
        t -= nt; b += c[i];
    }
    e = ei;
}

#define G1_GRID 576   // <=72 mtiles * 8 n-groups (4 n-tiles each)

// ---- gemmB: persistent gemm1 (bid < 576; 4 n-tiles/block = 32 K-steps) + W2^T tail ----
// Prologue (list gather + A-addr setup) amortized 4x; per-step body identical to R18.
__global__ __launch_bounds__(256) void gemmB_kernel(
    const unsigned short* __restrict__ xbf, const unsigned short* __restrict__ w1t,
    const float* __restrict__ b1, const int* __restrict__ list,
    const int* __restrict__ cnt, unsigned short* __restrict__ h,
    const float* __restrict__ w2, unsigned short* __restrict__ w2t)
{
    __shared__ char smem[25088] __attribute__((aligned(16)));   // union: gemm 25KB | transpose 16.6KB
    const int tid = threadIdx.x;

    if ((int)blockIdx.x >= G1_GRID) {
        // ---- W2 transpose to bf16 [e][o][h], 64x64 tiles ----
        float (*t)[65] = (float(*)[65])smem;
        const int loc = blockIdx.x - G1_GRID, e = loc >> 8, l2 = loc & 255;  // 32 r x 8 c
        const float* pin = w2 + (size_t)e * HID * OUTD;
        unsigned short* pout = w2t + (size_t)e * HID * OUTD;
        const int r0 = (l2 >> 3) * 64, c0 = (l2 & 7) * 64;
        const int r = tid >> 2, q = tid & 3;
        #pragma unroll
        for (int j = 0; j < 4; j++) {
            f32x4 v = *(const f32x4*)&pin[(size_t)(r0 + r) * OUTD + c0 + q * 16 + j * 4];
            #pragma unroll
            for (int i = 0; i < 4; i++) t[r][q * 16 + j * 4 + i] = v[i];
        }
        __syncthreads();
        unsigned short o[16];
        #pragma unroll
        for (int i = 0; i < 16; i++) o[i] = f2bf(t[q * 16 + i][r]);
        unsigned short* dst = &pout[(size_t)(c0 + r) * HID + r0 + q * 16];
        *(u16x8*)dst       = *(const u16x8*)&o[0];
        *(u16x8*)(dst + 8) = *(const u16x8*)&o[8];
        return;
    }

    unsigned short* ldsA = (unsigned short*)smem;            // 16KB
    unsigned short* ldsB = (unsigned short*)(smem + 16384);  // 8KB
    int* ldsTok = (int*)(smem + 24576);                      // 512B

    int e = 0, row0 = 0, bs = 0, m_e = 0, ntm = 0;
    tile_map128(cnt, 0, e, row0, bs, m_e, ntm);
    const int nwg = ntm * 8;                        // 8 n-groups (HID/256)
    bool valid; const int v = xcd_swizzle(blockIdx.x, nwg, valid);
    if (!valid) return;
    const int tile = v >> 3, ng = v & 7;
    tile_map128(cnt, tile, e, row0, bs, m_e, ntm);
    const int n0base = ng * 256;

    if (tid < 128) { int r = row0 + tid; if (r >= m_e) r = m_e - 1; ldsTok[tid] = list[e * N_TOK + r]; }
    __syncthreads();

    const int gslot = tid & 7;
    const unsigned short* aSrc[4];
    #pragma unroll
    for (int i = 0; i < 4; i++) {
        const int row = (i * 256 + tid) >> 3;       // 0..127
        const int col = ((gslot ^ (row & 7)) << 3);
        aSrc[i] = xbf + (size_t)ldsTok[row] * DIM + col;
    }
    const int brow0 = (tid >> 3), brow1 = (256 + tid) >> 3;  // 0..31, 32..63
    const int bcol0 = ((gslot ^ (brow0 & 7)) << 3);
    const int bcol1 = ((gslot ^ (brow1 & 7)) << 3);

    const int lane = tid & 63, wid = tid >> 6;
    const int wm = (wid >> 1) * 64, wn = (wid & 1) * 32;
    const int lrow = lane & 15, gk = lane >> 4, lm = lrow & 7;

    int rowA[4], rowB[2];
    #pragma unroll
    for (int f = 0; f < 4; f++) rowA[f] = (wm + f * 16 + lrow) * 64;
    #pragma unroll
    for (int f = 0; f < 2; f++) rowB[f] = (wn + f * 16 + lrow) * 64;

    const int hbase = bs + row0;

    for (int nt2 = 0; nt2 < 4; nt2++) {
        const int n0 = n0base + nt2 * 64;
        const unsigned short* bSrc[2];
        bSrc[0] = w1t + ((size_t)e * HID + n0 + brow0) * DIM + bcol0;
        bSrc[1] = w1t + ((size_t)e * HID + n0 + brow1) * DIM + bcol1;

        f32x4 acc[4][2] = {};
        for (int t = 0; t < 8; t++) {
            const int k0 = t * 64;
            __syncthreads();
            #pragma unroll
            for (int i = 0; i < 4; i++)
                gload16(aSrc[i] + k0, ldsA + ((i << 8) + (tid & 192)) * 8);
            #pragma unroll
            for (int i = 0; i < 2; i++)
                gload16(bSrc[i] + k0, ldsB + ((i << 8) + (tid & 192)) * 8);
            __syncthreads();
            #pragma unroll
            for (int kk = 0; kk < 2; kk++) {
                const int gsel = (((kk << 2) + gk) ^ lm) << 3;
                bf16x8 av[4], bv[2];
                #pragma unroll
                for (int f = 0; f < 4; f++)
                    av[f] = *(const bf16x8*)&ldsA[rowA[f] + gsel];
                #pragma unroll
                for (int f = 0; f < 2; f++)
                    bv[f] = *(const bf16x8*)&ldsB[rowB[f] + gsel];
                #pragma unroll
                for (int mf = 0; mf < 4; mf++)
                    #pragma unroll
                    for (int nf = 0; nf < 2; nf++)
                        acc[mf][nf] = MFMA_BF16(av[mf], bv[nf], acc[mf][nf], 0, 0, 0);
            }
        }

        float bias[2];
        #pragma unroll
        for (int nf = 0; nf < 2; nf++) bias[nf] = b1[e * HID + n0 + wn + nf * 16 + lrow];
        #pragma unroll
        for (int mf = 0; mf < 4; mf++) {
            #pragma unroll
            for (int j = 0; j < 4; j++) {
                const int m = wm + mf * 16 + gk * 4 + j;
                if (row0 + m < m_e) {
                    const size_t ro = (size_t)(hbase + m) * HID + n0 + wn;
                    #pragma unroll
                    for (int nf = 0; nf < 2; nf++) {
                        float vv = acc[mf][nf][j] + bias[nf];
                        h[ro + nf * 16 + lrow] = f2bf(vv > 0.f ? vv : 0.f);
                    }
                }
            }
        }
    }
}

// ---- GEMM2 (R14/R15, BK=128): out = h @ W2 + b2; K=2048 -> 16 K-steps ----
__global__ __launch_bounds__(256) void gemm2_kernel(
    const unsigned short* __restrict__ h, const unsigned short* __restrict__ w2t,
    const float* __restrict__ b2, const int* __restrict__ list,
    const int* __restrict__ cnt, float* __restrict__ out, float* __restrict__ counts)
{
    const int tid = threadIdx.x;
    if (blockIdx.x == 0 && tid < NEXP) counts[tid] = (float)cnt[tid];

    int e = 0, row0 = 0, bs = 0, m_e = 0, ntm = 0;
    tile_map128(cnt, 0, e, row0, bs, m_e, ntm);
    const int nwg = ntm * 8;                        // 8 n-tiles (OUTD/64)
    bool valid; const int v = xcd_swizzle(blockIdx.x, nwg, valid);
    if (!valid) return;
    const int tile = v >> 3, ntile = v & 7;
    tile_map128(cnt, tile, e, row0, bs, m_e, ntm);
    const int n0 = ntile * 64;

    __shared__ unsigned short ldsA[128 * 128] __attribute__((aligned(16)));  // 32KB
    __shared__ unsigned short ldsB[64 * 128]  __attribute__((aligned(16)));  // 16KB
    __shared__ int ldsTok[128];
    if (tid < 128) { int r = row0 + tid; if (r >= m_e) r = m_e - 1; ldsTok[tid] = list[e * N_TOK + r]; }
    __syncthreads();

    const unsigned short* aSrc[8]; const unsigned short* bSrc[4];
    #pragma unroll
    for (int i = 0; i < 8; i++) {
        const int g = i * 256 + tid, row = g >> 4, gc = g & 15;
        int slot = row0 + row; if (slot >= m_e) slot = m_e - 1;
        aSrc[i] = h + (size_t)(bs + slot) * HID + ((gc ^ (row & 15)) << 3);
    }
    #pragma unroll
    for (int i = 0; i < 4; i++) {
        const int g = i * 256 + tid, row = g >> 4, gc = g & 15;
        bSrc[i] = w2t + ((size_t)e * OUTD + n0 + row) * HID + ((gc ^ (row & 15)) << 3);
    }

    f32x4 acc[4][2] = {};
    const int lane = tid & 63, wid = tid >> 6;
    const int wm = (wid >> 1) * 64, wn = (wid & 1) * 32;
    const int lrow = lane & 15, gk = lane >> 4;

    int rowA[4], rowB[2];
    #pragma unroll
    for (int f = 0; f < 4; f++) rowA[f] = (wm + f * 16 + lrow) * 128;
    #pragma unroll
    for (int f = 0; f < 2; f++) rowB[f] = (wn + f * 16 + lrow) * 128;

    for (int t = 0; t < 16; t++) {
        const int k0 = t * 128;
        __syncthreads();
        #pragma unroll
        for (int i = 0; i < 8; i++)
            gload16(aSrc[i] + k0, ldsA + (i * 256 + tid) * 8);
        #pragma unroll
        for (int i = 0; i < 4; i++)
            gload16(bSrc[i] + k0, ldsB + (i * 256 + tid) * 8);
        __syncthreads();
        #pragma unroll
        for (int kk = 0; kk < 4; kk++) {
            const int gsel = (((kk << 2) + gk) ^ lrow) << 3;
            bf16x8 av[4], bv[2];
            #pragma unroll
            for (int f = 0; f < 4; f++)
                av[f] = *(const bf16x8*)&ldsA[rowA[f] + gsel];
            #pragma unroll
            for (int f = 0; f < 2; f++)
                bv[f] = *(const bf16x8*)&ldsB[rowB[f] + gsel];
            #pragma unroll
            for (int mf = 0; mf < 4; mf++)
                #pragma unroll
                for (int nf = 0; nf < 2; nf++)
                    acc[mf][nf] = MFMA_BF16(av[mf], bv[nf], acc[mf][nf], 0, 0, 0);
        }
    }

    float bias[2];
    #pragma unroll
    for (int nf = 0; nf < 2; nf++) bias[nf] = b2[e * OUTD + n0 + wn + nf * 16 + lrow];
    #pragma unroll
    for (int mf = 0; mf < 4; mf++) {
        #pragma unroll
        for (int j = 0; j < 4; j++) {
            const int m = wm + mf * 16 + gk * 4 + j;
            if (row0 + m < m_e) {
                const size_t ro = (size_t)ldsTok[m] * OUTD + n0 + wn;
                #pragma unroll
                for (int nf = 0; nf < 2; nf++)
                    out[ro + nf * 16 + lrow] = acc[mf][nf][j] + bias[nf];
            }
        }
    }
}

extern "C" void kernel_launch(void* const* d_in, const int* in_sizes, int n_in,
                              void* d_out, int out_size, void* d_ws, size_t ws_size,
                              hipStream_t stream) {
    (void)in_sizes; (void)n_in; (void)out_size; (void)ws_size;
    const float* x  = (const float*)d_in[0];
    const float* wr = (const float*)d_in[1];
    const float* br = (const float*)d_in[2];
    const float* w1 = (const float*)d_in[3];
    const float* b1 = (const float*)d_in[4];
    const float* w2 = (const float*)d_in[5];
    const float* b2 = (const float*)d_in[6];

    float* out    = (float*)d_out;
    float* probs  = out + (size_t)N_TOK * OUTD;
    float* counts = probs + (size_t)N_TOK * NEXP;

    char* ws = (char*)d_ws;
    int* cnt     = (int*)(ws + WS_CNT);
    int* list    = (int*)(ws + WS_LIST);
    unsigned short* xbf = (unsigned short*)(ws + WS_XBF);
    unsigned short* w1t = (unsigned short*)(ws + WS_W1T);
    unsigned short* w2t = (unsigned short*)(ws + WS_W2T);
    unsigned short* hbf = (unsigned short*)(ws + WS_H);

    hipMemsetAsync(cnt, 0, NEXP * sizeof(int), stream);
    k1_kernel<<<2304, 256, 0, stream>>>(x, wr, br, w1, probs, cnt, list, xbf, w1t);
    gemmB_kernel<<<G1_GRID + 2048, 256, 0, stream>>>(xbf, w1t, b1, list, cnt, hbf, w2, w2t);
    gemm2_kernel<<<568, 256, 0, stream>>>(hbf, w2t, b2, list, cnt, out, counts);
}

// Round 21
// 100.977 us; speedup vs baseline: 1.2975x; 1.2975x over previous
//
#include <hip/hip_runtime.h>
#include <hip/hip_bf16.h>
#include <stdint.h>

#define N_TOK 8192
#define DIM   512
#define HID   2048
#define OUTD  512
#define NEXP  8

typedef short  bf16x8 __attribute__((ext_vector_type(8)));
typedef float  f32x4  __attribute__((ext_vector_type(4)));
typedef unsigned short u16x8 __attribute__((ext_vector_type(8)));

// ---- workspace layout (bytes) ----
#define WS_CNT    0        // 8 ints
#define WS_LIST   4096     // 8*8192 ints
#define WS_XBF    266240   // 8192*512 bf16
#define WS_W1T    8654848  // 8*2048*512 bf16 ([e][h][d])
#define WS_W2T    25432064 // 8*512*2048 bf16 ([e][o][h])
#define WS_H      42209280 // 8192*2048 bf16

__device__ __forceinline__ unsigned short f2bf(float f) {
    uint32_t u = __builtin_bit_cast(uint32_t, f);
    u = (u + 0x7fffu + ((u >> 16) & 1u)) >> 16;   // RNE
    return (unsigned short)u;
}

// async global->LDS, 16B/lane; LDS dest = wave-uniform base + lane*16
__device__ __forceinline__ void gload16(const void* g, void* l) {
    __builtin_amdgcn_global_load_lds(
        (const __attribute__((address_space(1))) unsigned int*)g,
        (__attribute__((address_space(3))) unsigned int*)l, 16, 0, 0);
}

#define MFMA_BF16 __builtin_amdgcn_mfma_f32_16x16x32_bf16

// ======== k1: router+convert (bid 0..255) | W1 transpose (bid 256..2303) ========
__global__ __launch_bounds__(256) void k1_kernel(
    const float* __restrict__ x, const float* __restrict__ wr, const float* __restrict__ br,
    const float* __restrict__ w1,
    float* __restrict__ probs, int* __restrict__ cnt, int* __restrict__ list,
    unsigned short* __restrict__ xbf, unsigned short* __restrict__ w1t)
{
    const int bid = blockIdx.x, tid = threadIdx.x;
    if (bid < 256) {
        // ---- router: 32 tokens/block (4 waves x 8 serial), coalesced over D ----
        __shared__ int lcnt[NEXP], lbase[NEXP];
        __shared__ int am_l[32], slot_l[32];
        const int w = tid >> 6, lane = tid & 63;
        if (tid < NEXP) lcnt[tid] = 0;
        __syncthreads();
        for (int i = 0; i < 8; i++) {
            const int n = bid * 32 + w * 8 + i;
            float acc[NEXP] = {};
            #pragma unroll
            for (int db = 0; db < 8; db++) {
                const int d = db * 64 + lane;
                const float xv = x[(size_t)n * DIM + d];
                const f32x4 wv0 = *(const f32x4*)&wr[d * 8];
                const f32x4 wv1 = *(const f32x4*)&wr[d * 8 + 4];
                #pragma unroll
                for (int e = 0; e < 4; e++) { acc[e] += xv * wv0[e]; acc[4 + e] += xv * wv1[e]; }
            }
            #pragma unroll
            for (int m = 1; m < 64; m <<= 1)
                #pragma unroll
                for (int e = 0; e < NEXP; e++) acc[e] += __shfl_xor(acc[e], m, 64);
            #pragma unroll
            for (int e = 0; e < NEXP; e++) acc[e] += br[e];
            float mx = acc[0]; int am = 0;
            #pragma unroll
            for (int e = 1; e < NEXP; e++) if (acc[e] > mx) { mx = acc[e]; am = e; }
            float p[NEXP]; float s = 0.f;
            #pragma unroll
            for (int e = 0; e < NEXP; e++) { p[e] = expf(acc[e] - mx); s += p[e]; }
            const float inv = 1.f / s;
            if (lane == 0) {
                f32x4 p0, p1;
                #pragma unroll
                for (int e = 0; e < 4; e++) { p0[e] = p[e] * inv; p1[e] = p[e + 4] * inv; }
                *(f32x4*)&probs[(size_t)n * NEXP]     = p0;
                *(f32x4*)&probs[(size_t)n * NEXP + 4] = p1;
                const int slot = atomicAdd(&lcnt[am], 1);
                am_l[w * 8 + i] = am; slot_l[w * 8 + i] = slot;
            }
        }
        __syncthreads();
        if (tid < NEXP) lbase[tid] = atomicAdd(&cnt[tid], lcnt[tid]);
        __syncthreads();
        if (tid < 32) {
            const int a = am_l[tid];
            list[a * N_TOK + lbase[a] + slot_l[tid]] = bid * 32 + tid;
        }
        // ---- convert this block's 32 x-rows (L1-hot from router pass) ----
        const int row = bid * 32 + (tid >> 3), seg = tid & 7;
        const float* src = x + (size_t)row * DIM + seg * 64;
        unsigned short* dst = xbf + (size_t)row * DIM + seg * 64;
        #pragma unroll
        for (int j = 0; j < 8; j++) {
            f32x4 a = *(const f32x4*)&src[j * 8];
            f32x4 b = *(const f32x4*)&src[j * 8 + 4];
            u16x8 o;
            #pragma unroll
            for (int q2 = 0; q2 < 4; q2++) { o[q2] = f2bf(a[q2]); o[4 + q2] = f2bf(b[q2]); }
            *(u16x8*)&dst[j * 8] = o;
        }
    } else {
        // ---- W1 transpose to bf16 [e][h][d], 64x64 tiles, ILP-4 ----
        __shared__ float t[64][65];
        const int loc = bid - 256, e = loc >> 8, l2 = loc & 255;   // 8 r x 32 c
        const float* pin = w1 + (size_t)e * DIM * HID;
        unsigned short* pout = w1t + (size_t)e * DIM * HID;
        const int r0 = (l2 >> 5) * 64, c0 = (l2 & 31) * 64;
        const int r = tid >> 2, q = tid & 3;
        #pragma unroll
        for (int j = 0; j < 4; j++) {
            f32x4 v = *(const f32x4*)&pin[(size_t)(r0 + r) * HID + c0 + q * 16 + j * 4];
            #pragma unroll
            for (int i = 0; i < 4; i++) t[r][q * 16 + j * 4 + i] = v[i];
        }
        __syncthreads();
        unsigned short o[16];
        #pragma unroll
        for (int i = 0; i < 16; i++) o[i] = f2bf(t[q * 16 + i][r]);
        unsigned short* dst = &pout[(size_t)(c0 + r) * DIM + r0 + q * 16];
        *(u16x8*)dst       = *(const u16x8*)&o[0];
        *(u16x8*)(dst + 8) = *(const u16x8*)&o[8];
    }
}

// bijective per-XCD chunk swizzle
__device__ __forceinline__ int xcd_swizzle(int bid, int nwg, bool& valid) {
    const int xcd = bid & 7, cidx = bid >> 3;
    const int q = nwg >> 3, r = nwg & 7;
    const int csz = q + (xcd < r ? 1 : 0);
    valid = (cidx < csz);
    return (xcd < r ? xcd * (q + 1) : r * (q + 1) + (xcd - r) * q) + cidx;
}

// mt -> (expert, row0, base) from cnt[8]; 128-row tiles
__device__ __forceinline__ void tile_map128(const int* __restrict__ cnt, int tile,
                                            int& e, int& row0, int& bs, int& m_e, int& ntiles) {
    int c[NEXP]; ntiles = 0;
    #pragma unroll
    for (int i = 0; i < NEXP; i++) { c[i] = cnt[i]; ntiles += (c[i] + 127) >> 7; }
    int t = tile, b = 0, ei = 0;
    #pragma unroll
    for (int i = 0; i < NEXP; i++) {
        const int nt = (c[i] + 127) >> 7;
        if (t >= 0 && t < nt) { ei = i; row0 = t << 7; bs = b; m_e = c[i]; }
        t -= nt; b += c[i];
    }
    e = ei;
}

#define G1_GRID 2272   // <=71 mtiles * 32 ntiles

// ---- gemmB: gemm1 (bid < G1_GRID) + W2^T tail-appended (bid >= G1_GRID) ----
// R11/R18's proven combo: W2T blocks dispatch last, fill gemm1's retirement shadow.
__global__ __launch_bounds__(256) void gemmB_kernel(
    const unsigned short* __restrict__ xbf, const unsigned short* __restrict__ w1t,
    const float* __restrict__ b1, const int* __restrict__ list,
    const int* __restrict__ cnt, unsigned short* __restrict__ h,
    const float* __restrict__ w2, unsigned short* __restrict__ w2t)
{
    __shared__ char smem[25088] __attribute__((aligned(16)));   // union: gemm 25KB | transpose 16.6KB
    const int tid = threadIdx.x;

    if ((int)blockIdx.x >= G1_GRID) {
        // ---- W2 transpose to bf16 [e][o][h], 64x64 tiles ----
        float (*t)[65] = (float(*)[65])smem;
        const int loc = blockIdx.x - G1_GRID, e = loc >> 8, l2 = loc & 255;  // 32 r x 8 c
        const float* pin = w2 + (size_t)e * HID * OUTD;
        unsigned short* pout = w2t + (size_t)e * HID * OUTD;
        const int r0 = (l2 >> 3) * 64, c0 = (l2 & 7) * 64;
        const int r = tid >> 2, q = tid & 3;
        #pragma unroll
        for (int j = 0; j < 4; j++) {
            f32x4 v = *(const f32x4*)&pin[(size_t)(r0 + r) * OUTD + c0 + q * 16 + j * 4];
            #pragma unroll
            for (int i = 0; i < 4; i++) t[r][q * 16 + j * 4 + i] = v[i];
        }
        __syncthreads();
        unsigned short o[16];
        #pragma unroll
        for (int i = 0; i < 16; i++) o[i] = f2bf(t[q * 16 + i][r]);
        unsigned short* dst = &pout[(size_t)(c0 + r) * HID + r0 + q * 16];
        *(u16x8*)dst       = *(const u16x8*)&o[0];
        *(u16x8*)(dst + 8) = *(const u16x8*)&o[8];
        return;
    }

    unsigned short* ldsA = (unsigned short*)smem;            // 16KB
    unsigned short* ldsB = (unsigned short*)(smem + 16384);  // 8KB
    int* ldsTok = (int*)(smem + 24576);                      // 512B

    int e = 0, row0 = 0, bs = 0, m_e = 0, ntm = 0;
    tile_map128(cnt, 0, e, row0, bs, m_e, ntm);
    const int nwg = ntm * 32;                       // 32 n-tiles (HID/64)
    bool valid; const int v = xcd_swizzle(blockIdx.x, nwg, valid);
    if (!valid) return;
    const int tile = v >> 5, ntile = v & 31;
    tile_map128(cnt, tile, e, row0, bs, m_e, ntm);
    const int n0 = ntile * 64;

    if (tid < 128) { int r = row0 + tid; if (r >= m_e) r = m_e - 1; ldsTok[tid] = list[e * N_TOK + r]; }
    __syncthreads();

    const int gslot = tid & 7;
    const unsigned short* aSrc[4]; const unsigned short* bSrc[2];
    #pragma unroll
    for (int i = 0; i < 4; i++) {
        const int row = (i * 256 + tid) >> 3;       // 0..127
        const int col = ((gslot ^ (row & 7)) << 3);
        aSrc[i] = xbf + (size_t)ldsTok[row] * DIM + col;
    }
    #pragma unroll
    for (int i = 0; i < 2; i++) {
        const int row = (i * 256 + tid) >> 3;       // 0..63
        const int col = ((gslot ^ (row & 7)) << 3);
        bSrc[i] = w1t + ((size_t)e * HID + n0 + row) * DIM + col;
    }

    f32x4 acc[4][2] = {};
    const int lane = tid & 63, wid = tid >> 6;
    const int wm = (wid >> 1) * 64, wn = (wid & 1) * 32;
    const int lrow = lane & 15, gk = lane >> 4, lm = lrow & 7;

    int rowA[4], rowB[2];
    #pragma unroll
    for (int f = 0; f < 4; f++) rowA[f] = (wm + f * 16 + lrow) * 64;
    #pragma unroll
    for (int f = 0; f < 2; f++) rowB[f] = (wn + f * 16 + lrow) * 64;

    for (int t = 0; t < 8; t++) {
        const int k0 = t * 64;
        __syncthreads();
        #pragma unroll
        for (int i = 0; i < 4; i++)
            gload16(aSrc[i] + k0, ldsA + ((i << 8) + (tid & 192)) * 8);
        #pragma unroll
        for (int i = 0; i < 2; i++)
            gload16(bSrc[i] + k0, ldsB + ((i << 8) + (tid & 192)) * 8);
        __syncthreads();
        #pragma unroll
        for (int kk = 0; kk < 2; kk++) {
            const int gsel = (((kk << 2) + gk) ^ lm) << 3;
            bf16x8 av[4], bv[2];
            #pragma unroll
            for (int f = 0; f < 4; f++)
                av[f] = *(const bf16x8*)&ldsA[rowA[f] + gsel];
            #pragma unroll
            for (int f = 0; f < 2; f++)
                bv[f] = *(const bf16x8*)&ldsB[rowB[f] + gsel];
            #pragma unroll
            for (int mf = 0; mf < 4; mf++)
                #pragma unroll
                for (int nf = 0; nf < 2; nf++)
                    acc[mf][nf] = MFMA_BF16(av[mf], bv[nf], acc[mf][nf], 0, 0, 0);
        }
    }

    const int hbase = bs + row0;
    float bias[2];
    #pragma unroll
    for (int nf = 0; nf < 2; nf++) bias[nf] = b1[e * HID + n0 + wn + nf * 16 + lrow];
    #pragma unroll
    for (int mf = 0; mf < 4; mf++) {
        #pragma unroll
        for (int j = 0; j < 4; j++) {
            const int m = wm + mf * 16 + gk * 4 + j;
            if (row0 + m < m_e) {
                const size_t ro = (size_t)(hbase + m) * HID + n0 + wn;
                #pragma unroll
                for (int nf = 0; nf < 2; nf++) {
                    float vv = acc[mf][nf][j] + bias[nf];
                    h[ro + nf * 16 + lrow] = f2bf(vv > 0.f ? vv : 0.f);
                }
            }
        }
    }
}

// ---- GEMM2 (BK=128): out = h @ W2 + b2; K=2048 -> 16 K-steps ----
__global__ __launch_bounds__(256) void gemm2_kernel(
    const unsigned short* __restrict__ h, const unsigned short* __restrict__ w2t,
    const float* __restrict__ b2, const int* __restrict__ list,
    const int* __restrict__ cnt, float* __restrict__ out, float* __restrict__ counts)
{
    const int tid = threadIdx.x;
    if (blockIdx.x == 0 && tid < NEXP) counts[tid] = (float)cnt[tid];

    int e = 0, row0 = 0, bs = 0, m_e = 0, ntm = 0;
    tile_map128(cnt, 0, e, row0, bs, m_e, ntm);
    const int nwg = ntm * 8;                        // 8 n-tiles (OUTD/64)
    bool valid; const int v = xcd_swizzle(blockIdx.x, nwg, valid);
    if (!valid) return;
    const int tile = v >> 3, ntile = v & 7;
    tile_map128(cnt, tile, e, row0, bs, m_e, ntm);
    const int n0 = ntile * 64;

    __shared__ unsigned short ldsA[128 * 128] __attribute__((aligned(16)));  // 32KB
    __shared__ unsigned short ldsB[64 * 128]  __attribute__((aligned(16)));  // 16KB
    __shared__ int ldsTok[128];
    if (tid < 128) { int r = row0 + tid; if (r >= m_e) r = m_e - 1; ldsTok[tid] = list[e * N_TOK + r]; }
    __syncthreads();

    const unsigned short* aSrc[8]; const unsigned short* bSrc[4];
    #pragma unroll
    for (int i = 0; i < 8; i++) {
        const int g = i * 256 + tid, row = g >> 4, gc = g & 15;
        int slot = row0 + row; if (slot >= m_e) slot = m_e - 1;
        aSrc[i] = h + (size_t)(bs + slot) * HID + ((gc ^ (row & 15)) << 3);
    }
    #pragma unroll
    for (int i = 0; i < 4; i++) {
        const int g = i * 256 + tid, row = g >> 4, gc = g & 15;
        bSrc[i] = w2t + ((size_t)e * OUTD + n0 + row) * HID + ((gc ^ (row & 15)) << 3);
    }

    f32x4 acc[4][2] = {};
    const int lane = tid & 63, wid = tid >> 6;
    const int wm = (wid >> 1) * 64, wn = (wid & 1) * 32;
    const int lrow = lane & 15, gk = lane >> 4;

    int rowA[4], rowB[2];
    #pragma unroll
    for (int f = 0; f < 4; f++) rowA[f] = (wm + f * 16 + lrow) * 128;
    #pragma unroll
    for (int f = 0; f < 2; f++) rowB[f] = (wn + f * 16 + lrow) * 128;

    for (int t = 0; t < 16; t++) {
        const int k0 = t * 128;
        __syncthreads();
        #pragma unroll
        for (int i = 0; i < 8; i++)
            gload16(aSrc[i] + k0, ldsA + (i * 256 + tid) * 8);
        #pragma unroll
        for (int i = 0; i < 4; i++)
            gload16(bSrc[i] + k0, ldsB + (i * 256 + tid) * 8);
        __syncthreads();
        #pragma unroll
        for (int kk = 0; kk < 4; kk++) {
            const int gsel = (((kk << 2) + gk) ^ lrow) << 3;
            bf16x8 av[4], bv[2];
            #pragma unroll
            for (int f = 0; f < 4; f++)
                av[f] = *(const bf16x8*)&ldsA[rowA[f] + gsel];
            #pragma unroll
            for (int f = 0; f < 2; f++)
                bv[f] = *(const bf16x8*)&ldsB[rowB[f] + gsel];
            #pragma unroll
            for (int mf = 0; mf < 4; mf++)
                #pragma unroll
                for (int nf = 0; nf < 2; nf++)
                    acc[mf][nf] = MFMA_BF16(av[mf], bv[nf], acc[mf][nf], 0, 0, 0);
        }
    }

    float bias[2];
    #pragma unroll
    for (int nf = 0; nf < 2; nf++) bias[nf] = b2[e * OUTD + n0 + wn + nf * 16 + lrow];
    #pragma unroll
    for (int mf = 0; mf < 4; mf++) {
        #pragma unroll
        for (int j = 0; j < 4; j++) {
            const int m = wm + mf * 16 + gk * 4 + j;
            if (row0 + m < m_e) {
                const size_t ro = (size_t)ldsTok[m] * OUTD + n0 + wn;
                #pragma unroll
                for (int nf = 0; nf < 2; nf++)
                    out[ro + nf * 16 + lrow] = acc[mf][nf][j] + bias[nf];
            }
        }
    }
}

extern "C" void kernel_launch(void* const* d_in, const int* in_sizes, int n_in,
                              void* d_out, int out_size, void* d_ws, size_t ws_size,
                              hipStream_t stream) {
    (void)in_sizes; (void)n_in; (void)out_size; (void)ws_size;
    const float* x  = (const float*)d_in[0];
    const float* wr = (const float*)d_in[1];
    const float* br = (const float*)d_in[2];
    const float* w1 = (const float*)d_in[3];
    const float* b1 = (const float*)d_in[4];
    const float* w2 = (const float*)d_in[5];
    const float* b2 = (const float*)d_in[6];

    float* out    = (float*)d_out;
    float* probs  = out + (size_t)N_TOK * OUTD;
    float* counts = probs + (size_t)N_TOK * NEXP;

    char* ws = (char*)d_ws;
    int* cnt     = (int*)(ws + WS_CNT);
    int* list    = (int*)(ws + WS_LIST);
    unsigned short* xbf = (unsigned short*)(ws + WS_XBF);
    unsigned short* w1t = (unsigned short*)(ws + WS_W1T);
    unsigned short* w2t = (unsigned short*)(ws + WS_W2T);
    unsigned short* hbf = (unsigned short*)(ws + WS_H);

    hipMemsetAsync(cnt, 0, NEXP * sizeof(int), stream);
    k1_kernel<<<2304, 256, 0, stream>>>(x, wr, br, w1, probs, cnt, list, xbf, w1t);
    gemmB_kernel<<<G1_GRID + 2048, 256, 0, stream>>>(xbf, w1t, b1, list, cnt, hbf, w2, w2t);
    gemm2_kernel<<<568, 256, 0, stream>>>(hbf, w2t, b2, list, cnt, out, counts);
}